// Round 4
// baseline (594.050 us; speedup 1.0000x reference)
//
#include <hip/hip_runtime.h>

#define GRID_RES 64
#define C_CH     32
#define H_IMG    512
#define W_IMG    512
#define NBINS    512   // 4 batches x 16 (i0>>5) x 8 (j0>>6)
#define GPTS     1024  // sorted points per gather block

// ext_vector types for nontemporal builtins (HIP_vector_type is rejected)
typedef float    f32x4 __attribute__((ext_vector_type(4)));
typedef int      i32x4 __attribute__((ext_vector_type(4)));
typedef unsigned u32x4 __attribute__((ext_vector_type(4)));

// fp32 -> bf16 round-to-nearest-even
__device__ __forceinline__ ushort f32_to_bf16(float f) {
    union { float f; unsigned u; } a; a.f = f;
    unsigned r = (a.u + 0x7FFFu + ((a.u >> 16) & 1u)) >> 16;
    return (ushort)r;
}
__device__ __forceinline__ float bf16lo_to_f32(unsigned u) {
    union { unsigned u; float f; } a; a.u = u << 16; return a.f;
}
__device__ __forceinline__ float bf16hi_to_f32(unsigned u) {
    union { unsigned u; float f; } a; a.u = u & 0xFFFF0000u; return a.f;
}

// Shared projection (identical math in every pass -> bit-identical bins/outputs)
struct ProjOut {
    int   base;   // ushort-element offset into (B,HW,C) bf16 map
    int   dji;    // (j1-j0)*C_CH          in {0,32}
    int   dii;    // (i1-i0)*W_IMG*C_CH    in {0,16384}
    float di, dj, depth;
    int   bin;
};
__device__ __forceinline__ ProjOut project_pt(
    const i32x4 cc, const float* __restrict__ Km, const float* __restrict__ Pm)
{
    const float s = 2.0f / (float)(GRID_RES - 1);
    float wx = (float)cc.y * s - 1.0f;
    float wy = (float)cc.z * s - 1.0f;
    float wz = (float)cc.w * s - 1.0f;

    float cam0 = Pm[0]  * wx + Pm[1]  * wy + Pm[2]  * wz + Pm[3];
    float cam1 = Pm[4]  * wx + Pm[5]  * wy + Pm[6]  * wz + Pm[7];
    float cam2 = Pm[8]  * wx + Pm[9]  * wy + Pm[10] * wz + Pm[11];
    float cam3 = Pm[12] * wx + Pm[13] * wy + Pm[14] * wz + Pm[15];
    cam0 /= cam3; cam1 /= cam3; cam2 /= cam3;

    float g0 = Km[0] * cam0 + Km[1] * cam1 + Km[2] * cam2;
    float g1 = Km[3] * cam0 + Km[4] * cam1 + Km[5] * cam2;
    float g2 = Km[6] * cam0 + Km[7] * cam1 + Km[8] * cam2;
    float image_x = g0 / g2;
    float image_y = g1 / g2;

    float i0f = floorf(image_y);
    float j0f = floorf(image_x);
    float di = image_y - i0f;
    float dj = image_x - j0f;
    i0f = fminf(fmaxf(i0f, -1.0e9f), 1.0e9f);
    j0f = fminf(fmaxf(j0f, -1.0e9f), 1.0e9f);
    int i0r = (int)i0f;
    int j0r = (int)j0f;
    int i0 = min(max(i0r,     0), H_IMG - 1);
    int i1 = min(max(i0r + 1, 0), H_IMG - 1);
    int j0 = min(max(j0r,     0), W_IMG - 1);
    int j1 = min(max(j0r + 1, 0), W_IMG - 1);
    int b  = cc.x;

    ProjOut o;
    o.base  = ((b * H_IMG + i0) * W_IMG + j0) * C_CH;
    o.dji   = (j1 - j0) * C_CH;
    o.dii   = (i1 - i0) * W_IMG * C_CH;
    o.di    = di;
    o.dj    = dj;
    o.depth = cam2;
    o.bin   = b * 128 + (i0 >> 5) * 8 + (j0 >> 6);
    return o;
}

// ---------------------------------------------------------------------------
// Kernel 1: transpose+convert (B, C, H*W) fp32 -> (B, H*W, C) bf16.
// ---------------------------------------------------------------------------
__global__ __launch_bounds__(256) void transpose_bf16_kernel(
    const float* __restrict__ in, ushort* __restrict__ out)
{
    const int HW = H_IMG * W_IMG;
    __shared__ float tile[C_CH * 65];

    const int tilesPerBatch = HW / 64;
    const int b   = blockIdx.x / tilesPerBatch;
    const int t   = blockIdx.x % tilesPerBatch;
    const int hw0 = t * 64;
    const int tid = threadIdx.x;

    const int c_r = tid >> 3;
    const int u_r = (tid & 7) * 8;
    const f32x4* src = (const f32x4*)(in + ((size_t)(b * C_CH + c_r) * HW + hw0 + u_r));
    f32x4 v0 = __builtin_nontemporal_load(src);
    f32x4 v1 = __builtin_nontemporal_load(src + 1);
    float* d = &tile[c_r * 65 + u_r];
    d[0] = v0.x; d[1] = v0.y; d[2] = v0.z; d[3] = v0.w;
    d[4] = v1.x; d[5] = v1.y; d[6] = v1.z; d[7] = v1.w;

    __syncthreads();

    const int u_w = tid >> 2;
    const int c0  = (tid & 3) * 8;
    union { ushort us[8]; uint4 v; } pk;
#pragma unroll
    for (int k = 0; k < 8; ++k)
        pk.us[k] = f32_to_bf16(tile[(c0 + k) * 65 + u_w]);
    *(uint4*)(out + ((size_t)(b * HW + hw0 + u_w) * C_CH + c0)) = pk.v;
}

// ---------------------------------------------------------------------------
// init: zero hist + done counter.
// ---------------------------------------------------------------------------
__global__ __launch_bounds__(1024) void init_kernel(int* __restrict__ hist_done)
{
    if (threadIdx.x < NBINS + 1) hist_done[threadIdx.x] = 0;
}

// ---------------------------------------------------------------------------
// Fused hist + scan: per-point bin histogram (LDS-aggregated, flushed via
// device atomics), depth written here (this pass projects every point once).
// Last block to finish performs the 512-bin exclusive scan -> cursor.
// ---------------------------------------------------------------------------
__global__ __launch_bounds__(256) void hist_scan_kernel(
    const int* __restrict__ coords,
    const float* __restrict__ Km, const float* __restrict__ Pm,
    int* __restrict__ hist,       // [NBINS], zeroed
    int* __restrict__ done_ctr,   // [1], zeroed
    int* __restrict__ cursor,     // [NBINS] out
    float* __restrict__ out_depth,
    int N, int nblocks)
{
    __shared__ int lh[NBINS];
    const int tid = threadIdx.x;
    for (int i = tid; i < NBINS; i += 256) lh[i] = 0;
    __syncthreads();

    for (int p = blockIdx.x * 256 + tid; p < N; p += nblocks * 256) {
        i32x4 cc = __builtin_nontemporal_load((const i32x4*)coords + p);
        ProjOut o = project_pt(cc, Km, Pm);
        atomicAdd(&lh[o.bin], 1);
        __builtin_nontemporal_store(o.depth, out_depth + p);
    }
    __syncthreads();
    for (int i = tid; i < NBINS; i += 256)
        if (lh[i]) atomicAdd(&hist[i], lh[i]);

    // ---- last-block-done scan ----
    __threadfence();           // make hist atomics device-visible before ticket
    __syncthreads();
    __shared__ int is_last;
    if (tid == 0) is_last = (atomicAdd(done_ctr, 1) == nblocks - 1);
    __syncthreads();
    if (!is_last) return;

    __threadfence();
    __shared__ int sc[2][NBINS];
    // atomic reads guarantee we see the coherent final values
    int x0 = atomicAdd(&hist[tid], 0);
    int x1 = atomicAdd(&hist[tid + 256], 0);
    sc[0][tid] = x0;
    sc[0][tid + 256] = x1;
    __syncthreads();
    int s = 0;
    for (int off = 1; off < NBINS; off <<= 1) {
        const int i0 = tid, i1 = tid + 256;
        sc[s ^ 1][i0] = sc[s][i0] + (i0 >= off ? sc[s][i0 - off] : 0);
        sc[s ^ 1][i1] = sc[s][i1] + (i1 >= off ? sc[s][i1 - off] : 0);
        s ^= 1;
        __syncthreads();
    }
    cursor[tid]       = sc[s][tid]       - x0;   // exclusive prefix
    cursor[tid + 256] = sc[s][tid + 256] - x1;
}

// ---------------------------------------------------------------------------
// Scatter: sorted records {base, pidx|flags, di, dj}. 4096 pts/block ->
// per-bin chunks ~8 records (contiguous 128B runs). NT stores (read-once).
// ---------------------------------------------------------------------------
__global__ __launch_bounds__(1024) void scatter_kernel(
    const int* __restrict__ coords,
    const float* __restrict__ Km, const float* __restrict__ Pm,
    int* __restrict__ cursor,
    i32x4* __restrict__ records,
    int N)
{
    __shared__ int lh[NBINS];
    __shared__ int lbase[NBINS];
    const int tid = threadIdx.x;
    const int p0  = blockIdx.x * 4096;

    for (int i = tid; i < NBINS; i += 1024) lh[i] = 0;
    __syncthreads();

    int      binA[4], rankA[4], baseA[4];
    unsigned pfA[4];
    float    diA[4], djA[4];
#pragma unroll
    for (int k = 0; k < 4; ++k) {
        const int pp = p0 + k * 1024 + tid;
        binA[k] = -1;
        if (pp < N) {
            i32x4 cc = __builtin_nontemporal_load((const i32x4*)coords + pp);
            ProjOut o = project_pt(cc, Km, Pm);
            binA[k]  = o.bin;
            baseA[k] = o.base;
            diA[k]   = o.di;
            djA[k]   = o.dj;
            pfA[k]   = (unsigned)pp
                     | ((unsigned)(o.dji != 0) << 30)
                     | ((unsigned)(o.dii != 0) << 31);
            rankA[k] = atomicAdd(&lh[o.bin], 1);
        }
    }
    __syncthreads();

    for (int i = tid; i < NBINS; i += 1024) {
        int c = lh[i];
        if (c) lbase[i] = atomicAdd(&cursor[i], c);
    }
    __syncthreads();

#pragma unroll
    for (int k = 0; k < 4; ++k) {
        if (binA[k] >= 0) {
            const int slot = lbase[binA[k]] + rankA[k];
            i32x4 rec;
            rec.x = baseA[k];
            rec.y = (int)pfA[k];
            rec.z = __float_as_int(diA[k]);
            rec.w = __float_as_int(djA[k]);
            __builtin_nontemporal_store(rec, records + slot);
        }
    }
}

// ---------------------------------------------------------------------------
// Gather from sorted records: 1024 points/block (one tile's worth) -> L1+L2
// reuse; XCD-chunk swizzle keeps each tile's blocks on one XCD.
// Interpolation math identical to the unsorted kernel.
// ---------------------------------------------------------------------------
__global__ __launch_bounds__(256) void gather_sorted_kernel(
    const i32x4*  __restrict__ records,
    const ushort* __restrict__ feat,
    float* __restrict__ out_feat,
    int N, int swz_q, int swz_r)
{
    // bijective XCD-chunk swizzle (m204)
    const int orig = blockIdx.x;
    const int xcd  = orig & 7;
    const int idx  = orig >> 3;
    const int wg   = (xcd < swz_r ? xcd * (swz_q + 1)
                                  : swz_r * (swz_q + 1) + (xcd - swz_r) * swz_q) + idx;
    const int s0   = wg * GPTS;

    __shared__ int      s_base[GPTS];
    __shared__ unsigned s_pf[GPTS];
    __shared__ float    s_di[GPTS];
    __shared__ float    s_dj[GPTS];

    const int tid = threadIdx.x;
    for (int k = tid; k < GPTS; k += 256) {
        if (s0 + k < N) {
            i32x4 rec = __builtin_nontemporal_load(records + s0 + k);
            s_base[k] = rec.x;
            s_pf[k]   = (unsigned)rec.y;
            s_di[k]   = __int_as_float(rec.z);
            s_dj[k]   = __int_as_float(rec.w);
        }
    }
    __syncthreads();

    const int cq   = tid & 3;    // channel octet
    const int slot = tid >> 2;   // 0..63
#pragma unroll
    for (int it = 0; it < GPTS / 64; ++it) {
        const int lp = it * 64 + slot;
        if (s0 + lp < N) {
            const unsigned pf = s_pf[lp];
            const int   base = s_base[lp] + cq * 8;
            const int   dji  = (int)((pf >> 30) & 1u) << 5;    // {0,32}
            const int   dii  = (int)((pf >> 31) & 1u) << 14;   // {0,16384}
            const int   pidx = (int)(pf & 0x3FFFFFFFu);
            const float fdi  = s_di[lp];
            const float fdj  = s_dj[lp];

            const u32x4 u00 = *(const u32x4*)(feat + base);
            const u32x4 u01 = *(const u32x4*)(feat + base + dji);
            const u32x4 u10 = *(const u32x4*)(feat + base + dii);
            const u32x4 u11 = *(const u32x4*)(feat + base + dii + dji);

            float o[8];
            const unsigned* a00 = (const unsigned*)&u00;
            const unsigned* a01 = (const unsigned*)&u01;
            const unsigned* a10 = (const unsigned*)&u10;
            const unsigned* a11 = (const unsigned*)&u11;
#pragma unroll
            for (int k = 0; k < 4; ++k) {
                float f00 = bf16lo_to_f32(a00[k]), f01 = bf16lo_to_f32(a01[k]);
                float f10 = bf16lo_to_f32(a10[k]), f11 = bf16lo_to_f32(a11[k]);
                float r0 = f00 + fdi * (f10 - f00);
                float r1 = f01 + fdi * (f11 - f01);
                o[2 * k] = r0 + fdj * (r1 - r0);
                f00 = bf16hi_to_f32(a00[k]); f01 = bf16hi_to_f32(a01[k]);
                f10 = bf16hi_to_f32(a10[k]); f11 = bf16hi_to_f32(a11[k]);
                r0 = f00 + fdi * (f10 - f00);
                r1 = f01 + fdi * (f11 - f01);
                o[2 * k + 1] = r0 + fdj * (r1 - r0);
            }
            float* op = out_feat + (size_t)pidx * C_CH + cq * 8;
            f32x4 lo4 = { o[0], o[1], o[2], o[3] };
            f32x4 hi4 = { o[4], o[5], o[6], o[7] };
            __builtin_nontemporal_store(lo4, (f32x4*)op);
            __builtin_nontemporal_store(hi4, (f32x4*)(op + 4));
        }
    }
}

// ---------------------------------------------------------------------------
// Fallback A (ws fits map only): unsorted bf16 gather.
// ---------------------------------------------------------------------------
__global__ __launch_bounds__(256) void gather_bf16_kernel(
    const int*    __restrict__ coords,
    const ushort* __restrict__ feat,
    const float*  __restrict__ Km,
    const float*  __restrict__ Pm,
    float* __restrict__ out_feat,
    float* __restrict__ out_depth,
    int N)
{
    __shared__ int   s_base[256];
    __shared__ int   s_dji[256];
    __shared__ int   s_dii[256];
    __shared__ float s_fdi[256];
    __shared__ float s_fdj[256];

    const int tid = threadIdx.x;
    const int p0  = blockIdx.x * 256;

    {
        const int p = p0 + tid;
        if (p < N) {
            i32x4 cc = __builtin_nontemporal_load((const i32x4*)coords + p);
            ProjOut o = project_pt(cc, Km, Pm);
            s_base[tid] = o.base;
            s_dji[tid]  = o.dji;
            s_dii[tid]  = o.dii;
            s_fdi[tid]  = o.di;
            s_fdj[tid]  = o.dj;
            __builtin_nontemporal_store(o.depth, out_depth + p);
        }
    }
    __syncthreads();

    const int cq   = tid & 3;
    const int slot = tid >> 2;
#pragma unroll
    for (int it = 0; it < 4; ++it) {
        const int lp = it * 64 + slot;
        const int p  = p0 + lp;
        if (p < N) {
            const int   base = s_base[lp] + cq * 8;
            const int   dji  = s_dji[lp];
            const int   dii  = s_dii[lp];
            const float fdi  = s_fdi[lp];
            const float fdj  = s_fdj[lp];

            const u32x4 u00 = *(const u32x4*)(feat + base);
            const u32x4 u01 = *(const u32x4*)(feat + base + dji);
            const u32x4 u10 = *(const u32x4*)(feat + base + dii);
            const u32x4 u11 = *(const u32x4*)(feat + base + dii + dji);

            float o[8];
            const unsigned* a00 = (const unsigned*)&u00;
            const unsigned* a01 = (const unsigned*)&u01;
            const unsigned* a10 = (const unsigned*)&u10;
            const unsigned* a11 = (const unsigned*)&u11;
#pragma unroll
            for (int k = 0; k < 4; ++k) {
                float f00 = bf16lo_to_f32(a00[k]), f01 = bf16lo_to_f32(a01[k]);
                float f10 = bf16lo_to_f32(a10[k]), f11 = bf16lo_to_f32(a11[k]);
                float r0 = f00 + fdi * (f10 - f00);
                float r1 = f01 + fdi * (f11 - f01);
                o[2 * k] = r0 + fdj * (r1 - r0);
                f00 = bf16hi_to_f32(a00[k]); f01 = bf16hi_to_f32(a01[k]);
                f10 = bf16hi_to_f32(a10[k]); f11 = bf16hi_to_f32(a11[k]);
                r0 = f00 + fdi * (f10 - f00);
                r1 = f01 + fdi * (f11 - f01);
                o[2 * k + 1] = r0 + fdj * (r1 - r0);
            }
            float* op = out_feat + (size_t)p * C_CH + cq * 8;
            f32x4 lo4 = { o[0], o[1], o[2], o[3] };
            f32x4 hi4 = { o[4], o[5], o[6], o[7] };
            __builtin_nontemporal_store(lo4, (f32x4*)op);
            __builtin_nontemporal_store(hi4, (f32x4*)(op + 4));
        }
    }
}

// ---------------------------------------------------------------------------
// Fallback B (no workspace): direct gather from raw BCHW fp32.
// ---------------------------------------------------------------------------
__global__ __launch_bounds__(64) void gather_fp32_direct_kernel(
    const int*   __restrict__ coords,
    const float* __restrict__ feat,
    const float* __restrict__ Km,
    const float* __restrict__ Pm,
    float* __restrict__ out_feat,
    float* __restrict__ out_depth,
    int N)
{
    const int tid = threadIdx.x;
    const int p0  = blockIdx.x * 2;
    const int HW  = H_IMG * W_IMG;

    __shared__ int   s_base[2];
    __shared__ int   s_dji[2];
    __shared__ int   s_dii[2];
    __shared__ float s_fdi[2];
    __shared__ float s_fdj[2];

    if (tid < 2) {
        const int p = p0 + tid;
        if (p < N) {
            i32x4 cc = ((const i32x4*)coords)[p];
            const float s = 2.0f / (float)(GRID_RES - 1);
            float wx = (float)cc.y * s - 1.0f;
            float wy = (float)cc.z * s - 1.0f;
            float wz = (float)cc.w * s - 1.0f;
            float cam0 = Pm[0]  * wx + Pm[1]  * wy + Pm[2]  * wz + Pm[3];
            float cam1 = Pm[4]  * wx + Pm[5]  * wy + Pm[6]  * wz + Pm[7];
            float cam2 = Pm[8]  * wx + Pm[9]  * wy + Pm[10] * wz + Pm[11];
            float cam3 = Pm[12] * wx + Pm[13] * wy + Pm[14] * wz + Pm[15];
            cam0 /= cam3; cam1 /= cam3; cam2 /= cam3;
            float g0 = Km[0] * cam0 + Km[1] * cam1 + Km[2] * cam2;
            float g1 = Km[3] * cam0 + Km[4] * cam1 + Km[5] * cam2;
            float g2 = Km[6] * cam0 + Km[7] * cam1 + Km[8] * cam2;
            float image_x = g0 / g2;
            float image_y = g1 / g2;
            float i0f = floorf(image_y);
            float j0f = floorf(image_x);
            float di = image_y - i0f;
            float dj = image_x - j0f;
            i0f = fminf(fmaxf(i0f, -1.0e9f), 1.0e9f);
            j0f = fminf(fmaxf(j0f, -1.0e9f), 1.0e9f);
            int i0r = (int)i0f;
            int j0r = (int)j0f;
            int i0 = min(max(i0r,     0), H_IMG - 1);
            int i1 = min(max(i0r + 1, 0), H_IMG - 1);
            int j0 = min(max(j0r,     0), W_IMG - 1);
            int j1 = min(max(j0r + 1, 0), W_IMG - 1);
            int b  = cc.x;
            s_base[tid] = (b * C_CH * H_IMG + i0) * W_IMG + j0;
            s_dji[tid]  = (j1 - j0);
            s_dii[tid]  = (i1 - i0) * W_IMG;
            s_fdi[tid]  = di;
            s_fdj[tid]  = dj;
            out_depth[p] = cam2;
        }
    }
    __syncthreads();

    const int c  = tid & 31;
    const int lp = tid >> 5;
    const int p  = p0 + lp;
    if (p < N) {
        const int   base = s_base[lp];
        const int   dji  = s_dji[lp];
        const int   dii  = s_dii[lp];
        const float fdi  = s_fdi[lp];
        const float fdj  = s_fdj[lp];
        const float* fp = feat + base + (size_t)c * HW;
        float f00 = fp[0];
        float f01 = fp[dji];
        float f10 = fp[dii];
        float f11 = fp[dii + dji];
        float r0 = f00 + fdi * (f10 - f00);
        float r1 = f01 + fdi * (f11 - f01);
        out_feat[(size_t)p * C_CH + c] = r0 + fdj * (r1 - r0);
    }
}

extern "C" void kernel_launch(void* const* d_in, const int* in_sizes, int n_in,
                              void* d_out, int out_size, void* d_ws, size_t ws_size,
                              hipStream_t stream)
{
    const int*   coords = (const int*)  d_in[0];
    const float* feat   = (const float*)d_in[1];
    const float* Km     = (const float*)d_in[2];
    const float* Pm     = (const float*)d_in[3];

    const int N  = in_sizes[0] / 4;
    const int HW = H_IMG * W_IMG;
    const int Bb = in_sizes[1] / (C_CH * HW);

    float* out_feat  = (float*)d_out;
    float* out_depth = out_feat + (size_t)N * C_CH;

    const size_t map_bytes  = (size_t)in_sizes[1] * sizeof(ushort); // bf16 map (64MB)
    const size_t rec_bytes  = (size_t)N * 16;                       // sorted records
    const size_t meta_bytes = (NBINS + 1 + NBINS) * sizeof(int);    // hist+done+cursor
    const size_t need_full  = map_bytes + rec_bytes + meta_bytes + 256;

    if (ws_size >= need_full) {
        char* ws = (char*)d_ws;
        ushort* tfeat   = (ushort*)ws;                      ws += map_bytes;
        i32x4*  records = (i32x4*)ws;                       ws += rec_bytes;
        int*    hist    = (int*)ws;   // [NBINS] then done[1] then cursor[NBINS]
        int*    done    = hist + NBINS;
        int*    cursor  = done + 1;

        const int nwg   = (N + GPTS - 1) / GPTS;
        const int swz_q = nwg / 8;
        const int swz_r = nwg % 8;
        const int hist_blocks = 1024;

        transpose_bf16_kernel<<<Bb * (HW / 64), 256, 0, stream>>>(feat, tfeat);
        init_kernel<<<1, 1024, 0, stream>>>(hist);
        hist_scan_kernel<<<hist_blocks, 256, 0, stream>>>(
            coords, Km, Pm, hist, done, cursor, out_depth, N, hist_blocks);
        scatter_kernel<<<(N + 4095) / 4096, 1024, 0, stream>>>(
            coords, Km, Pm, cursor, records, N);
        gather_sorted_kernel<<<nwg, 256, 0, stream>>>(
            records, tfeat, out_feat, N, swz_q, swz_r);
    } else if (ws_size >= map_bytes) {
        ushort* tfeat = (ushort*)d_ws;
        transpose_bf16_kernel<<<Bb * (HW / 64), 256, 0, stream>>>(feat, tfeat);
        gather_bf16_kernel<<<(N + 255) / 256, 256, 0, stream>>>(
            coords, tfeat, Km, Pm, out_feat, out_depth, N);
    } else {
        gather_fp32_direct_kernel<<<(N + 1) / 2, 64, 0, stream>>>(
            coords, feat, Km, Pm, out_feat, out_depth, N);
    }
}

// Round 5
// 474.633 us; speedup vs baseline: 1.2516x; 1.2516x over previous
//
#include <hip/hip_runtime.h>

#define GRID_RES 64
#define C_CH     32
#define H_IMG    512
#define W_IMG    512

// ext_vector types for nontemporal builtins (HIP_vector_type is rejected)
typedef float    f32x4 __attribute__((ext_vector_type(4)));
typedef int      i32x4 __attribute__((ext_vector_type(4)));
typedef unsigned u32x4 __attribute__((ext_vector_type(4)));

// fp32 -> bf16 round-to-nearest-even (inputs are finite normals; NaN path unused)
__device__ __forceinline__ ushort f32_to_bf16(float f) {
    union { float f; unsigned u; } a; a.f = f;
    unsigned r = (a.u + 0x7FFFu + ((a.u >> 16) & 1u)) >> 16;
    return (ushort)r;
}
__device__ __forceinline__ float bf16lo_to_f32(unsigned u) {
    union { unsigned u; float f; } a; a.u = u << 16; return a.f;
}
__device__ __forceinline__ float bf16hi_to_f32(unsigned u) {
    union { unsigned u; float f; } a; a.u = u & 0xFFFF0000u; return a.f;
}

// ---------------------------------------------------------------------------
// Kernel 1: transpose+convert (B, C, H*W) fp32 -> (B, H*W, C) bf16.
// LDS tile 32(c) x 64(hw), stride 65 => 2-way bank aliasing only (free).
// Source fp32 is read-once: non-temporal loads keep it out of L3 so the
// bf16 map (written normally, cached) stays resident for the gather.
// ---------------------------------------------------------------------------
__global__ __launch_bounds__(256) void transpose_bf16_kernel(
    const float* __restrict__ in, ushort* __restrict__ out)
{
    const int HW = H_IMG * W_IMG;
    __shared__ float tile[C_CH * 65];

    const int tilesPerBatch = HW / 64;
    const int b   = blockIdx.x / tilesPerBatch;
    const int t   = blockIdx.x % tilesPerBatch;
    const int hw0 = t * 64;
    const int tid = threadIdx.x;

    // read phase: coalesced along HW. c_r in 0..31, u_r = (tid&7)*8
    const int c_r = tid >> 3;
    const int u_r = (tid & 7) * 8;
    const f32x4* src = (const f32x4*)(in + ((size_t)(b * C_CH + c_r) * HW + hw0 + u_r));
    f32x4 v0 = __builtin_nontemporal_load(src);
    f32x4 v1 = __builtin_nontemporal_load(src + 1);
    float* d = &tile[c_r * 65 + u_r];
    d[0] = v0.x; d[1] = v0.y; d[2] = v0.z; d[3] = v0.w;
    d[4] = v1.x; d[5] = v1.y; d[6] = v1.z; d[7] = v1.w;

    __syncthreads();

    // write phase: u_w (pixel) in 0..63, c0 in {0,8,16,24}; 16B bf16x8 store
    const int u_w = tid >> 2;
    const int c0  = (tid & 3) * 8;
    union { ushort us[8]; uint4 v; } pk;
#pragma unroll
    for (int k = 0; k < 8; ++k)
        pk.us[k] = f32_to_bf16(tile[(c0 + k) * 65 + u_w]);
    *(uint4*)(out + ((size_t)(b * HW + hw0 + u_w) * C_CH + c0)) = pk.v;
}

// ---------------------------------------------------------------------------
// Kernel 2 (bf16 path): projection + bilinear gather from (B,HW,C) bf16 map.
// 256 points / 256-thread block.
// Phase A: every thread projects one point, records params to LDS, writes
//          depth (non-temporal).
// Phase B: lane = channel-octet (tid&3, 8 channels = one dwordx4), slot =
//          tid>>2; each corner is ONE uint4 load (4 lanes cover the 64B
//          corner segment).
// Output written non-temporally (write-once) so the 264MB stream does not
// evict the 64MB bf16 map from L3.
// ---------------------------------------------------------------------------
__global__ __launch_bounds__(256) void gather_bf16_kernel(
    const int*    __restrict__ coords,
    const ushort* __restrict__ feat,
    const float*  __restrict__ Km,
    const float*  __restrict__ Pm,
    float* __restrict__ out_feat,
    float* __restrict__ out_depth,
    int N)
{
    __shared__ int   s_base[256];
    __shared__ int   s_dji[256];
    __shared__ int   s_dii[256];
    __shared__ float s_fdi[256];
    __shared__ float s_fdj[256];

    const int tid = threadIdx.x;
    const int p0  = blockIdx.x * 256;

    {
        const int p = p0 + tid;
        if (p < N) {
            i32x4 cc = __builtin_nontemporal_load((const i32x4*)coords + p);
            const float s = 2.0f / (float)(GRID_RES - 1);
            float wx = (float)cc.y * s - 1.0f;
            float wy = (float)cc.z * s - 1.0f;
            float wz = (float)cc.w * s - 1.0f;

            float cam0 = Pm[0]  * wx + Pm[1]  * wy + Pm[2]  * wz + Pm[3];
            float cam1 = Pm[4]  * wx + Pm[5]  * wy + Pm[6]  * wz + Pm[7];
            float cam2 = Pm[8]  * wx + Pm[9]  * wy + Pm[10] * wz + Pm[11];
            float cam3 = Pm[12] * wx + Pm[13] * wy + Pm[14] * wz + Pm[15];
            cam0 /= cam3; cam1 /= cam3; cam2 /= cam3;

            float g0 = Km[0] * cam0 + Km[1] * cam1 + Km[2] * cam2;
            float g1 = Km[3] * cam0 + Km[4] * cam1 + Km[5] * cam2;
            float g2 = Km[6] * cam0 + Km[7] * cam1 + Km[8] * cam2;
            float image_x = g0 / g2;
            float image_y = g1 / g2;

            float i0f = floorf(image_y);
            float j0f = floorf(image_x);
            float di = image_y - i0f;
            float dj = image_x - j0f;
            i0f = fminf(fmaxf(i0f, -1.0e9f), 1.0e9f);
            j0f = fminf(fmaxf(j0f, -1.0e9f), 1.0e9f);
            int i0r = (int)i0f;
            int j0r = (int)j0f;
            int i0 = min(max(i0r,     0), H_IMG - 1);
            int i1 = min(max(i0r + 1, 0), H_IMG - 1);
            int j0 = min(max(j0r,     0), W_IMG - 1);
            int j1 = min(max(j0r + 1, 0), W_IMG - 1);
            int b  = cc.x;

            s_base[tid] = ((b * H_IMG + i0) * W_IMG + j0) * C_CH;
            s_dji[tid]  = (j1 - j0) * C_CH;
            s_dii[tid]  = (i1 - i0) * W_IMG * C_CH;
            s_fdi[tid]  = di;
            s_fdj[tid]  = dj;
            __builtin_nontemporal_store(cam2, out_depth + p);
        }
    }
    __syncthreads();

    const int cq   = tid & 3;    // channel octet: channels 8cq .. 8cq+7
    const int slot = tid >> 2;   // 0..63
#pragma unroll
    for (int it = 0; it < 4; ++it) {
        const int lp = it * 64 + slot;
        const int p  = p0 + lp;
        if (p < N) {
            const int   base = s_base[lp] + cq * 8;
            const int   dji  = s_dji[lp];
            const int   dii  = s_dii[lp];
            const float fdi  = s_fdi[lp];
            const float fdj  = s_fdj[lp];

            const u32x4 u00 = *(const u32x4*)(feat + base);
            const u32x4 u01 = *(const u32x4*)(feat + base + dji);
            const u32x4 u10 = *(const u32x4*)(feat + base + dii);
            const u32x4 u11 = *(const u32x4*)(feat + base + dii + dji);

            float o[8];
            const unsigned* a00 = (const unsigned*)&u00;
            const unsigned* a01 = (const unsigned*)&u01;
            const unsigned* a10 = (const unsigned*)&u10;
            const unsigned* a11 = (const unsigned*)&u11;
#pragma unroll
            for (int k = 0; k < 4; ++k) {
                // low channel (8cq + 2k)
                float f00 = bf16lo_to_f32(a00[k]), f01 = bf16lo_to_f32(a01[k]);
                float f10 = bf16lo_to_f32(a10[k]), f11 = bf16lo_to_f32(a11[k]);
                float r0 = f00 + fdi * (f10 - f00);
                float r1 = f01 + fdi * (f11 - f01);
                o[2 * k] = r0 + fdj * (r1 - r0);
                // high channel (8cq + 2k + 1)
                f00 = bf16hi_to_f32(a00[k]); f01 = bf16hi_to_f32(a01[k]);
                f10 = bf16hi_to_f32(a10[k]); f11 = bf16hi_to_f32(a11[k]);
                r0 = f00 + fdi * (f10 - f00);
                r1 = f01 + fdi * (f11 - f01);
                o[2 * k + 1] = r0 + fdj * (r1 - r0);
            }
            float* op = out_feat + (size_t)p * C_CH + cq * 8;
            f32x4 lo4 = { o[0], o[1], o[2], o[3] };
            f32x4 hi4 = { o[4], o[5], o[6], o[7] };
            __builtin_nontemporal_store(lo4, (f32x4*)op);
            __builtin_nontemporal_store(hi4, (f32x4*)(op + 4));
        }
    }
}

// ---------------------------------------------------------------------------
// Fallback (no workspace): direct gather from raw BCHW fp32.
// ---------------------------------------------------------------------------
__global__ __launch_bounds__(64) void gather_fp32_direct_kernel(
    const int*   __restrict__ coords,
    const float* __restrict__ feat,
    const float* __restrict__ Km,
    const float* __restrict__ Pm,
    float* __restrict__ out_feat,
    float* __restrict__ out_depth,
    int N)
{
    const int tid = threadIdx.x;
    const int p0  = blockIdx.x * 2;
    const int HW  = H_IMG * W_IMG;

    __shared__ int   s_base[2];
    __shared__ int   s_dji[2];
    __shared__ int   s_dii[2];
    __shared__ float s_fdi[2];
    __shared__ float s_fdj[2];

    if (tid < 2) {
        const int p = p0 + tid;
        if (p < N) {
            i32x4 cc = ((const i32x4*)coords)[p];
            const float s = 2.0f / (float)(GRID_RES - 1);
            float wx = (float)cc.y * s - 1.0f;
            float wy = (float)cc.z * s - 1.0f;
            float wz = (float)cc.w * s - 1.0f;
            float cam0 = Pm[0]  * wx + Pm[1]  * wy + Pm[2]  * wz + Pm[3];
            float cam1 = Pm[4]  * wx + Pm[5]  * wy + Pm[6]  * wz + Pm[7];
            float cam2 = Pm[8]  * wx + Pm[9]  * wy + Pm[10] * wz + Pm[11];
            float cam3 = Pm[12] * wx + Pm[13] * wy + Pm[14] * wz + Pm[15];
            cam0 /= cam3; cam1 /= cam3; cam2 /= cam3;
            float g0 = Km[0] * cam0 + Km[1] * cam1 + Km[2] * cam2;
            float g1 = Km[3] * cam0 + Km[4] * cam1 + Km[5] * cam2;
            float g2 = Km[6] * cam0 + Km[7] * cam1 + Km[8] * cam2;
            float image_x = g0 / g2;
            float image_y = g1 / g2;
            float i0f = floorf(image_y);
            float j0f = floorf(image_x);
            float di = image_y - i0f;
            float dj = image_x - j0f;
            i0f = fminf(fmaxf(i0f, -1.0e9f), 1.0e9f);
            j0f = fminf(fmaxf(j0f, -1.0e9f), 1.0e9f);
            int i0r = (int)i0f;
            int j0r = (int)j0f;
            int i0 = min(max(i0r,     0), H_IMG - 1);
            int i1 = min(max(i0r + 1, 0), H_IMG - 1);
            int j0 = min(max(j0r,     0), W_IMG - 1);
            int j1 = min(max(j0r + 1, 0), W_IMG - 1);
            int b  = cc.x;
            s_base[tid] = (b * C_CH * H_IMG + i0) * W_IMG + j0;
            s_dji[tid]  = (j1 - j0);
            s_dii[tid]  = (i1 - i0) * W_IMG;
            s_fdi[tid]  = di;
            s_fdj[tid]  = dj;
            out_depth[p] = cam2;
        }
    }
    __syncthreads();

    const int c  = tid & 31;
    const int lp = tid >> 5;
    const int p  = p0 + lp;
    if (p < N) {
        const int   base = s_base[lp];
        const int   dji  = s_dji[lp];
        const int   dii  = s_dii[lp];
        const float fdi  = s_fdi[lp];
        const float fdj  = s_fdj[lp];
        const float* fp = feat + base + (size_t)c * HW;
        float f00 = fp[0];
        float f01 = fp[dji];
        float f10 = fp[dii];
        float f11 = fp[dii + dji];
        float r0 = f00 + fdi * (f10 - f00);
        float r1 = f01 + fdi * (f11 - f01);
        out_feat[(size_t)p * C_CH + c] = r0 + fdj * (r1 - r0);
    }
}

extern "C" void kernel_launch(void* const* d_in, const int* in_sizes, int n_in,
                              void* d_out, int out_size, void* d_ws, size_t ws_size,
                              hipStream_t stream)
{
    const int*   coords = (const int*)  d_in[0];
    const float* feat   = (const float*)d_in[1];
    const float* Km     = (const float*)d_in[2];
    const float* Pm     = (const float*)d_in[3];

    const int N  = in_sizes[0] / 4;
    const int HW = H_IMG * W_IMG;
    const int Bb = in_sizes[1] / (C_CH * HW);

    float* out_feat  = (float*)d_out;
    float* out_depth = out_feat + (size_t)N * C_CH;

    const size_t need = (size_t)in_sizes[1] * sizeof(ushort);  // bf16 map

    if (ws_size >= need) {
        ushort* tfeat = (ushort*)d_ws;
        transpose_bf16_kernel<<<Bb * (HW / 64), 256, 0, stream>>>(feat, tfeat);
        gather_bf16_kernel<<<(N + 255) / 256, 256, 0, stream>>>(
            coords, tfeat, Km, Pm, out_feat, out_depth, N);
    } else {
        gather_fp32_direct_kernel<<<(N + 1) / 2, 64, 0, stream>>>(
            coords, feat, Km, Pm, out_feat, out_depth, N);
    }
}